// Round 1
// baseline (3502.867 us; speedup 1.0000x reference)
//
#include <hip/hip_runtime.h>
#include <hip/hip_bf16.h>
#include <math.h>

#define BB 8
#define NN 512
#define DD 512
#define NH 16
#define DH 32
#define TD 1536
#define NG 32
#define MAXD 128

// ---------------- LayerNorm: one block per row ----------------
__global__ __launch_bounds__(256) void ln_kernel(const float* __restrict__ x,
                                                 const float* __restrict__ g,
                                                 const float* __restrict__ b,
                                                 float* __restrict__ out) {
    const int row = blockIdx.x;
    const int tid = threadIdx.x;
    const float* xr = x + (size_t)row * DD;
    float v0 = xr[tid], v1 = xr[tid + 256];
    __shared__ float s1[256], s2[256];
    s1[tid] = v0 + v1;
    s2[tid] = v0 * v0 + v1 * v1;
    __syncthreads();
    for (int off = 128; off > 0; off >>= 1) {
        if (tid < off) { s1[tid] += s1[tid + off]; s2[tid] += s2[tid + off]; }
        __syncthreads();
    }
    const float mean = s1[0] * (1.0f / DD);
    const float var  = s2[0] * (1.0f / DD) - mean * mean;
    const float rs   = rsqrtf(var + 1e-5f);
    float* orow = out + (size_t)row * DD;
    orow[tid]       = (v0 - mean) * rs * g[tid]       + b[tid];
    orow[tid + 256] = (v1 - mean) * rs * g[tid + 256] + b[tid + 256];
}

// ---------------- Generic tiled fp32 GEMM: C = A @ W^T + bias (+gelu)(+res) -
// A: [M][K] row-major, W: [Nout][K] row-major
template <bool GELU, bool RES>
__global__ __launch_bounds__(256) void gemm_kernel(const float* __restrict__ A,
                                                   const float* __restrict__ W,
                                                   const float* __restrict__ bias,
                                                   const float* __restrict__ res,
                                                   float* __restrict__ C,
                                                   int M, int Nout, int K) {
    const int bm = blockIdx.y * 64;
    const int bn = blockIdx.x * 64;
    __shared__ float As[16][68];
    __shared__ float Ws[16][68];
    const int tid = threadIdx.x;
    const int tx = tid & 15;   // col group
    const int ty = tid >> 4;   // row group
    float acc[4][4] = {};
    for (int k0 = 0; k0 < K; k0 += 16) {
#pragma unroll
        for (int l = 0; l < 4; l++) {
            int idx = tid + l * 256;
            int r = idx >> 4, c = idx & 15;
            As[c][r] = A[(size_t)(bm + r) * K + k0 + c];
            Ws[c][r] = W[(size_t)(bn + r) * K + k0 + c];
        }
        __syncthreads();
#pragma unroll
        for (int kk = 0; kk < 16; kk++) {
            float a[4], w[4];
#pragma unroll
            for (int i = 0; i < 4; i++) a[i] = As[kk][ty * 4 + i];
#pragma unroll
            for (int j = 0; j < 4; j++) w[j] = Ws[kk][tx * 4 + j];
#pragma unroll
            for (int i = 0; i < 4; i++)
#pragma unroll
                for (int j = 0; j < 4; j++) acc[i][j] += a[i] * w[j];
        }
        __syncthreads();
    }
#pragma unroll
    for (int i = 0; i < 4; i++) {
        const int row = bm + ty * 4 + i;
#pragma unroll
        for (int j = 0; j < 4; j++) {
            const int col = bn + tx * 4 + j;
            float v = acc[i][j] + bias[col];
            if (GELU) v = 0.5f * v * (1.0f + erff(v * 0.70710678118654752f));
            if (RES)  v += res[(size_t)row * Nout + col];
            C[(size_t)row * Nout + col] = v;
        }
    }
}

// ---------------- Fused attention: one block per (b, q) ----------------
// scores[h][k] = (q_h . k_h)/sqrt(32) + dist_emb[dc][h] + rbf_b[h] + sum_g e_g * rbf_w[h][g]
// softmax over k, then ctx[h][d] = sum_k p * V
__global__ __launch_bounds__(256) void attn_kernel(const float* __restrict__ qkv,     // [B*N][1536]
                                                   const int* __restrict__ dist,      // [B][N][N]
                                                   const float* __restrict__ dist3d,  // [B][N][N]
                                                   const float* __restrict__ demb,    // [128][16]
                                                   const float* __restrict__ rbfw,    // [16][32]
                                                   const float* __restrict__ rbfb,    // [16]
                                                   float* __restrict__ ctx_out)       // [B*N][512]
{
    const int q = blockIdx.x;
    const int b = blockIdx.y;
    const int tid = threadIdx.x;

    __shared__ float qs[DD];
    __shared__ float sc[NH][NN];   // 32 KB
    __shared__ float red[NH][17];

    const float scale = 0.17677669529663687f;  // 1/sqrt(32)
    const float* qrow = qkv + (size_t)(b * NN + q) * TD;
    qs[tid]       = qrow[tid] * scale;
    qs[tid + 256] = qrow[tid + 256] * scale;
    __syncthreads();

    const float STEP  = 20.0f / 31.0f;
    const float COEFF = -0.5f / (STEP * STEP);

    // ---- scores + bias ----
    for (int kk = tid; kk < NN; kk += 256) {
        const float* krow = qkv + (size_t)(b * NN + kk) * TD + DD;
        int dc = dist[((size_t)b * NN + q) * NN + kk];
        dc = min(max(dc, 0), MAXD - 1);
        const float d3 = dist3d[((size_t)b * NN + q) * NN + kk];
        float e[NG];
#pragma unroll
        for (int g = 0; g < NG; g++) {
            float t = d3 - (float)g * STEP;
            e[g] = __expf(COEFF * t * t);
        }
        for (int h = 0; h < NH; h++) {
            float dot = 0.f;
#pragma unroll
            for (int d = 0; d < DH; d++) dot += qs[h * DH + d] * krow[h * DH + d];
            float bv = demb[dc * NH + h] + rbfb[h];
#pragma unroll
            for (int g = 0; g < NG; g++) bv += e[g] * rbfw[h * NG + g];
            sc[h][kk] = dot + bv;
        }
    }
    __syncthreads();

    // ---- softmax (16 threads per head) ----
    const int h = tid >> 4;
    const int lane = tid & 15;
    float m = -1e30f;
    for (int kk = lane; kk < NN; kk += 16) m = fmaxf(m, sc[h][kk]);
    red[h][lane] = m;
    __syncthreads();
    if (lane == 0) {
        float mm = red[h][0];
#pragma unroll
        for (int i = 1; i < 16; i++) mm = fmaxf(mm, red[h][i]);
        red[h][16] = mm;
    }
    __syncthreads();
    m = red[h][16];
    float s = 0.f;
    for (int kk = lane; kk < NN; kk += 16) {
        float p = __expf(sc[h][kk] - m);
        sc[h][kk] = p;
        s += p;
    }
    __syncthreads();
    red[h][lane] = s;
    __syncthreads();
    if (lane == 0) {
        float ss = 0.f;
#pragma unroll
        for (int i = 0; i < 16; i++) ss += red[h][i];
        red[h][16] = 1.0f / ss;
    }
    __syncthreads();
    const float rinv = red[h][16];

    // ---- ctx: thread (h, lane) does d = lane, lane+16 ----
    float acc0 = 0.f, acc1 = 0.f;
    const float* vbase = qkv + (size_t)b * NN * TD + 2 * DD + h * DH;
    for (int kk = 0; kk < NN; kk++) {
        const float p = sc[h][kk];
        const float* vrow = vbase + (size_t)kk * TD;
        acc0 += p * vrow[lane];
        acc1 += p * vrow[lane + 16];
    }
    float* crow = ctx_out + (size_t)(b * NN + q) * DD;
    crow[h * DH + lane]      = acc0 * rinv;
    crow[h * DH + lane + 16] = acc1 * rinv;
}

extern "C" void kernel_launch(void* const* d_in, const int* in_sizes, int n_in,
                              void* d_out, int out_size, void* d_ws, size_t ws_size,
                              hipStream_t stream) {
    const float* x      = (const float*)d_in[0];
    const int*   dist   = (const int*)d_in[1];
    const float* dist3d = (const float*)d_in[2];
    const float* n1g    = (const float*)d_in[3];
    const float* n1b    = (const float*)d_in[4];
    const float* win    = (const float*)d_in[5];
    const float* bin    = (const float*)d_in[6];
    const float* wo     = (const float*)d_in[7];
    const float* bo     = (const float*)d_in[8];
    const float* demb   = (const float*)d_in[9];
    const float* rbfw   = (const float*)d_in[10];
    const float* rbfb   = (const float*)d_in[11];
    const float* n2g    = (const float*)d_in[12];
    const float* n2b    = (const float*)d_in[13];
    const float* w1     = (const float*)d_in[14];
    const float* b1     = (const float*)d_in[15];
    const float* w2     = (const float*)d_in[16];
    const float* b2     = (const float*)d_in[17];
    float* out = (float*)d_out;
    float* ws  = (float*)d_ws;

    const size_t M1 = (size_t)1024 * 1024;
    float* h    = ws;                 // 2M floats  [4096][512]
    float* qkv  = ws + 2 * M1;        // 6M floats  [4096][1536]
    float* ctx  = ws + 8 * M1;        // 2M floats  [4096][512]
    float* hres = ws + 10 * M1;       // 2M floats
    float* h2   = ws + 12 * M1;       // 2M floats
    float* mid  = ws + 14 * M1;       // 8M floats  [4096][2048]

    const int M = BB * NN;  // 4096

    ln_kernel<<<M, 256, 0, stream>>>(x, n1g, n1b, h);
    gemm_kernel<false, false><<<dim3(TD / 64, M / 64), 256, 0, stream>>>(
        h, win, bin, nullptr, qkv, M, TD, DD);
    attn_kernel<<<dim3(NN, BB), 256, 0, stream>>>(qkv, dist, dist3d, demb, rbfw, rbfb, ctx);
    gemm_kernel<false, true><<<dim3(DD / 64, M / 64), 256, 0, stream>>>(
        ctx, wo, bo, h, hres, M, DD, DD);
    ln_kernel<<<M, 256, 0, stream>>>(hres, n2g, n2b, h2);
    gemm_kernel<true, false><<<dim3(2048 / 64, M / 64), 256, 0, stream>>>(
        h2, w1, b1, nullptr, mid, M, 2048, DD);
    gemm_kernel<false, true><<<dim3(DD / 64, M / 64), 256, 0, stream>>>(
        mid, w2, b2, hres, out, M, DD, 2048);
}

// Round 2
// 662.701 us; speedup vs baseline: 5.2857x; 5.2857x over previous
//
#include <hip/hip_runtime.h>
#include <hip/hip_bf16.h>
#include <math.h>

#define BB 8
#define NN 512
#define DD 512
#define NH 16
#define DH 32
#define TD 1536
#define NG 32
#define MAXD 128

typedef __attribute__((ext_vector_type(8))) short bf16x8;
typedef __attribute__((ext_vector_type(4))) float f32x4;

__device__ inline short f2bf(float x) {
    __hip_bfloat16 h = __float2bfloat16(x);
    return *reinterpret_cast<short*>(&h);
}

// ---------------- LayerNorm: one block per row ----------------
__global__ __launch_bounds__(256) void ln_kernel(const float* __restrict__ x,
                                                 const float* __restrict__ g,
                                                 const float* __restrict__ b,
                                                 float* __restrict__ out) {
    const int row = blockIdx.x;
    const int tid = threadIdx.x;
    const float* xr = x + (size_t)row * DD;
    float v0 = xr[tid], v1 = xr[tid + 256];
    __shared__ float s1[256], s2[256];
    s1[tid] = v0 + v1;
    s2[tid] = v0 * v0 + v1 * v1;
    __syncthreads();
    for (int off = 128; off > 0; off >>= 1) {
        if (tid < off) { s1[tid] += s1[tid + off]; s2[tid] += s2[tid + off]; }
        __syncthreads();
    }
    const float mean = s1[0] * (1.0f / DD);
    const float var  = s2[0] * (1.0f / DD) - mean * mean;
    const float rs   = rsqrtf(var + 1e-5f);
    float* orow = out + (size_t)row * DD;
    orow[tid]       = (v0 - mean) * rs * g[tid]       + b[tid];
    orow[tid + 256] = (v1 - mean) * rs * g[tid + 256] + b[tid + 256];
}

// ---------------- Generic tiled fp32 GEMM: C = A @ W^T + bias (+gelu)(+res) -
template <bool GELU, bool RES>
__global__ __launch_bounds__(256) void gemm_kernel(const float* __restrict__ A,
                                                   const float* __restrict__ W,
                                                   const float* __restrict__ bias,
                                                   const float* __restrict__ res,
                                                   float* __restrict__ C,
                                                   int M, int Nout, int K) {
    const int bm = blockIdx.y * 64;
    const int bn = blockIdx.x * 64;
    __shared__ float As[16][68];
    __shared__ float Ws[16][68];
    const int tid = threadIdx.x;
    const int tx = tid & 15;
    const int ty = tid >> 4;
    float acc[4][4] = {};
    for (int k0 = 0; k0 < K; k0 += 16) {
#pragma unroll
        for (int l = 0; l < 4; l++) {
            int idx = tid + l * 256;
            int r = idx >> 4, c = idx & 15;
            As[c][r] = A[(size_t)(bm + r) * K + k0 + c];
            Ws[c][r] = W[(size_t)(bn + r) * K + k0 + c];
        }
        __syncthreads();
#pragma unroll
        for (int kk = 0; kk < 16; kk++) {
            float a[4], w[4];
#pragma unroll
            for (int i = 0; i < 4; i++) a[i] = As[kk][ty * 4 + i];
#pragma unroll
            for (int j = 0; j < 4; j++) w[j] = Ws[kk][tx * 4 + j];
#pragma unroll
            for (int i = 0; i < 4; i++)
#pragma unroll
                for (int j = 0; j < 4; j++) acc[i][j] += a[i] * w[j];
        }
        __syncthreads();
    }
#pragma unroll
    for (int i = 0; i < 4; i++) {
        const int row = bm + ty * 4 + i;
#pragma unroll
        for (int j = 0; j < 4; j++) {
            const int col = bn + tx * 4 + j;
            float v = acc[i][j] + bias[col];
            if (GELU) v = 0.5f * v * (1.0f + erff(v * 0.70710678118654752f));
            if (RES)  v += res[(size_t)row * Nout + col];
            C[(size_t)row * Nout + col] = v;
        }
    }
}

// ---------------- MFMA flash attention ----------------
// Block: (b, q-tile of 16). 512 threads = 8 waves, 2 heads per wave.
// k-chunks of 16, K/V staged in LDS bf16. Bias computed via MFMA:
//   bias[(q,k)][h] = e[(q,k)][g] * rbf_w[h][g]  (C init = dist_emb + rbf_b)
__global__ __launch_bounds__(512) void attn_mfma(
    const float* __restrict__ qkv,     // [4096][1536]
    const int* __restrict__ dist,      // [B][N][N]
    const float* __restrict__ dist3d,  // [B][N][N]
    const float* __restrict__ demb,    // [128][16]
    const float* __restrict__ rbfw,    // [16][32]
    const float* __restrict__ rbfb,    // [16]
    float* __restrict__ ctx)           // [4096][512]
{
    const int b    = blockIdx.y;
    const int q0   = blockIdx.x * 16;
    const int tid  = threadIdx.x;
    const int wave = tid >> 6;
    const int lane = tid & 63;
    const int l16  = lane & 15;
    const int quad = lane >> 4;

    __shared__ short Kc[NH * 16 * 32];      // [h][k16][d32] bf16, 16 KB
    __shared__ short Vc[NH * 16 * 32];      // [h][k16][d32] bf16, 16 KB
    __shared__ float biasT[16 * 16 * 17];   // [q][k][h pad 17] fp32, 17 KB
    __shared__ short Pb[8 * 16 * 32];       // per-wave [q16][k32] bf16, 8 KB

    // zero Pb (upper k halves must stay zero for the zero-padded PV MFMA)
    for (int i = tid; i < 8 * 16 * 32; i += 512) Pb[i] = 0;

    const float scale = 0.17677669529663687f;  // 1/sqrt(32)
    // Q fragments for this wave's 2 heads (A-layout: row=l16, k=quad*8+j), scale folded
    bf16x8 qf[2];
#pragma unroll
    for (int h = 0; h < 2; h++) {
        const int hh = wave * 2 + h;
        const float* src = qkv + (size_t)(b * NN + q0 + l16) * TD + hh * DH + quad * 8;
#pragma unroll
        for (int j = 0; j < 8; j++) qf[h][j] = f2bf(src[j] * scale);
    }
    // w fragment for bias MFMA: B[g][h] = rbfw[h][g]; lane holds g=quad*8+j, h=l16
    bf16x8 wf;
#pragma unroll
    for (int j = 0; j < 8; j++) wf[j] = f2bf(rbfw[l16 * NG + quad * 8 + j]);

    f32x4 O[2][2];
    float mrun[2][4], lrun[2][4];
#pragma unroll
    for (int h = 0; h < 2; h++) {
#pragma unroll
        for (int t = 0; t < 2; t++) O[h][t] = (f32x4){0.f, 0.f, 0.f, 0.f};
#pragma unroll
        for (int r = 0; r < 4; r++) { mrun[h][r] = -1e30f; lrun[h][r] = 0.f; }
    }

    const float STEP  = 20.0f / 31.0f;
    const float COEFF = -0.5f / (STEP * STEP);

    for (int c = 0; c < 32; c++) {
        const int k0 = c * 16;
        __syncthreads();
        // ---- stage K,V chunk: 16 rows x 512 dims, fp32 -> bf16 ----
#pragma unroll
        for (int l = 0; l < 8; l++) {
            const int idx = tid + l * 512;        // float2 id, 4096 total
            const int k   = idx >> 8;
            const int d2  = (idx & 255) * 2;
            const int h   = d2 >> 5, dd = d2 & 31;
            const float* kp = qkv + (size_t)(b * NN + k0 + k) * TD + DD + d2;
            const float* vp = kp + DD;
            const unsigned kpack = (unsigned)(unsigned short)f2bf(kp[0]) |
                                   ((unsigned)(unsigned short)f2bf(kp[1]) << 16);
            const unsigned vpack = (unsigned)(unsigned short)f2bf(vp[0]) |
                                   ((unsigned)(unsigned short)f2bf(vp[1]) << 16);
            ((unsigned*)Kc)[(h * 512 + k * 32 + dd) >> 1] = kpack;
            ((unsigned*)Vc)[(h * 512 + k * 32 + dd) >> 1] = vpack;
        }
        // ---- bias MFMA: wave handles q-rows wave*2, wave*2+1 ----
#pragma unroll
        for (int g = 0; g < 2; g++) {
            const int qloc = wave * 2 + g;
            const size_t rowbase = ((size_t)(b * NN) + q0 + qloc) * NN + k0;
            const float d3 = dist3d[rowbase + l16];
            bf16x8 ef;
#pragma unroll
            for (int j = 0; j < 8; j++) {
                const float t = d3 - (float)(quad * 8 + j) * STEP;
                ef[j] = f2bf(__expf(COEFF * t * t));
            }
            f32x4 cc;
            const float rb = rbfb[l16];
#pragma unroll
            for (int r = 0; r < 4; r++) {
                int dc = dist[rowbase + quad * 4 + r];
                dc = min(max(dc, 0), MAXD - 1);
                cc[r] = demb[dc * NH + l16] + rb;
            }
            const f32x4 dres = __builtin_amdgcn_mfma_f32_16x16x32_bf16(ef, wf, cc, 0, 0, 0);
#pragma unroll
            for (int r = 0; r < 4; r++)
                biasT[(qloc * 16 + quad * 4 + r) * 17 + l16] = dres[r];
        }
        __syncthreads();
        // ---- per-head: QK^T MFMA, bias add, online softmax, PV MFMA ----
#pragma unroll
        for (int h = 0; h < 2; h++) {
            const int hh = wave * 2 + h;
            const bf16x8 kf = *(const bf16x8*)&Kc[hh * 512 + l16 * 32 + quad * 8];
            f32x4 s = __builtin_amdgcn_mfma_f32_16x16x32_bf16(
                qf[h], kf, (f32x4){0.f, 0.f, 0.f, 0.f}, 0, 0, 0);
            float sv[4], mx[4], al[4], pv[4], ps[4];
#pragma unroll
            for (int r = 0; r < 4; r++) {
                sv[r] = s[r] + biasT[((quad * 4 + r) * 16 + l16) * 17 + hh];
                mx[r] = sv[r];
            }
#pragma unroll
            for (int m = 1; m < 16; m <<= 1)
#pragma unroll
                for (int r = 0; r < 4; r++) mx[r] = fmaxf(mx[r], __shfl_xor(mx[r], m));
#pragma unroll
            for (int r = 0; r < 4; r++) {
                const float mn = fmaxf(mrun[h][r], mx[r]);
                al[r] = __expf(mrun[h][r] - mn);
                pv[r] = __expf(sv[r] - mn);
                mrun[h][r] = mn;
                ps[r] = pv[r];
            }
#pragma unroll
            for (int m = 1; m < 16; m <<= 1)
#pragma unroll
                for (int r = 0; r < 4; r++) ps[r] += __shfl_xor(ps[r], m);
#pragma unroll
            for (int r = 0; r < 4; r++) {
                lrun[h][r] = lrun[h][r] * al[r] + ps[r];
                Pb[wave * 512 + (quad * 4 + r) * 32 + l16] = f2bf(pv[r]);
#pragma unroll
                for (int t = 0; t < 2; t++) O[h][t][r] *= al[r];
            }
            const bf16x8 pf = *(const bf16x8*)&Pb[wave * 512 + l16 * 32 + quad * 8];
#pragma unroll
            for (int t = 0; t < 2; t++) {
                bf16x8 vf;
                if (quad < 2) {
#pragma unroll
                    for (int j = 0; j < 8; j++)
                        vf[j] = Vc[hh * 512 + (quad * 8 + j) * 32 + t * 16 + l16];
                } else {
#pragma unroll
                    for (int j = 0; j < 8; j++) vf[j] = 0;
                }
                O[h][t] = __builtin_amdgcn_mfma_f32_16x16x32_bf16(pf, vf, O[h][t], 0, 0, 0);
            }
        }
    }
    // ---- epilogue ----
#pragma unroll
    for (int h = 0; h < 2; h++) {
        const int hh = wave * 2 + h;
#pragma unroll
        for (int r = 0; r < 4; r++) {
            const float rinv = 1.0f / lrun[h][r];
            const size_t row = (size_t)(b * NN + q0 + quad * 4 + r);
#pragma unroll
            for (int t = 0; t < 2; t++)
                ctx[row * DD + hh * DH + t * 16 + l16] = O[h][t][r] * rinv;
        }
    }
}

extern "C" void kernel_launch(void* const* d_in, const int* in_sizes, int n_in,
                              void* d_out, int out_size, void* d_ws, size_t ws_size,
                              hipStream_t stream) {
    const float* x      = (const float*)d_in[0];
    const int*   dist   = (const int*)d_in[1];
    const float* dist3d = (const float*)d_in[2];
    const float* n1g    = (const float*)d_in[3];
    const float* n1b    = (const float*)d_in[4];
    const float* win    = (const float*)d_in[5];
    const float* bin    = (const float*)d_in[6];
    const float* wo     = (const float*)d_in[7];
    const float* bo     = (const float*)d_in[8];
    const float* demb   = (const float*)d_in[9];
    const float* rbfw   = (const float*)d_in[10];
    const float* rbfb   = (const float*)d_in[11];
    const float* n2g    = (const float*)d_in[12];
    const float* n2b    = (const float*)d_in[13];
    const float* w1     = (const float*)d_in[14];
    const float* b1     = (const float*)d_in[15];
    const float* w2     = (const float*)d_in[16];
    const float* b2     = (const float*)d_in[17];
    float* out = (float*)d_out;
    float* ws  = (float*)d_ws;

    const size_t M1 = (size_t)1024 * 1024;
    float* h    = ws;                 // [4096][512]
    float* qkv  = ws + 2 * M1;        // [4096][1536]
    float* ctx  = ws + 8 * M1;        // [4096][512]
    float* hres = ws + 10 * M1;
    float* h2   = ws + 12 * M1;
    float* mid  = ws + 14 * M1;       // [4096][2048]

    const int M = BB * NN;  // 4096

    ln_kernel<<<M, 256, 0, stream>>>(x, n1g, n1b, h);
    gemm_kernel<false, false><<<dim3(TD / 64, M / 64), 256, 0, stream>>>(
        h, win, bin, nullptr, qkv, M, TD, DD);
    attn_mfma<<<dim3(NN / 16, BB), 512, 0, stream>>>(qkv, dist, dist3d, demb, rbfw, rbfb, ctx);
    gemm_kernel<false, true><<<dim3(DD / 64, M / 64), 256, 0, stream>>>(
        ctx, wo, bo, h, hres, M, DD, DD);
    ln_kernel<<<M, 256, 0, stream>>>(hres, n2g, n2b, h2);
    gemm_kernel<true, false><<<dim3(2048 / 64, M / 64), 256, 0, stream>>>(
        h2, w1, b1, nullptr, mid, M, 2048, DD);
    gemm_kernel<false, true><<<dim3(DD / 64, M / 64), 256, 0, stream>>>(
        mid, w2, b2, hres, out, M, DD, 2048);
}

// Round 3
// 351.531 us; speedup vs baseline: 9.9646x; 1.8852x over previous
//
#include <hip/hip_runtime.h>
#include <hip/hip_bf16.h>
#include <math.h>

#define BB 8
#define NN 512
#define DD 512
#define NH 16
#define DH 32
#define TD 1536
#define NG 32
#define MAXD 128

typedef __attribute__((ext_vector_type(8))) short bf16x8;
typedef __attribute__((ext_vector_type(4))) float f32x4;

__device__ inline short f2bf(float x) {
    __hip_bfloat16 h = __float2bfloat16(x);
    return *reinterpret_cast<short*>(&h);
}

// async 16B global->LDS. lds dest must be WAVE-UNIFORM base; lane i lands at base + i*16.
__device__ inline void gld_lds16(const void* g, void* l) {
    __builtin_amdgcn_global_load_lds(
        (const __attribute__((address_space(1))) unsigned int*)g,
        (__attribute__((address_space(3))) unsigned int*)l, 16, 0, 0);
}

// ---------------- weight fp32 -> bf16 convert (4 arrays in one launch) ------
__global__ __launch_bounds__(256) void cvt_weights(
    const float* __restrict__ s0, const float* __restrict__ s1,
    const float* __restrict__ s2, const float* __restrict__ s3,
    short* __restrict__ d0, short* __restrict__ d1,
    short* __restrict__ d2, short* __restrict__ d3,
    int n0, int n1, int n2, int n3) {
    const float* s; short* d; int n;
    switch (blockIdx.y) {
        case 0: s = s0; d = d0; n = n0; break;
        case 1: s = s1; d = d1; n = n1; break;
        case 2: s = s2; d = d2; n = n2; break;
        default: s = s3; d = d3; n = n3; break;
    }
    const int i = (blockIdx.x * 256 + threadIdx.x) * 4;
    if (i >= n) return;
    const float4 v = *(const float4*)(s + i);
    short4 o;
    o.x = f2bf(v.x); o.y = f2bf(v.y); o.z = f2bf(v.z); o.w = f2bf(v.w);
    *(short4*)(d + i) = o;
}

// ---------------- LayerNorm: bf16 out (+ optional fp32 copy for residual) ---
__global__ __launch_bounds__(256) void ln_kernel(const float* __restrict__ x,
                                                 const float* __restrict__ g,
                                                 const float* __restrict__ b,
                                                 short* __restrict__ out_bf,
                                                 float* __restrict__ out_f) {
    const int row = blockIdx.x;
    const int tid = threadIdx.x;
    const float* xr = x + (size_t)row * DD;
    float v0 = xr[tid], v1 = xr[tid + 256];
    __shared__ float s1[256], s2[256];
    s1[tid] = v0 + v1;
    s2[tid] = v0 * v0 + v1 * v1;
    __syncthreads();
    for (int off = 128; off > 0; off >>= 1) {
        if (tid < off) { s1[tid] += s1[tid + off]; s2[tid] += s2[tid + off]; }
        __syncthreads();
    }
    const float mean = s1[0] * (1.0f / DD);
    const float var  = s2[0] * (1.0f / DD) - mean * mean;
    const float rs   = rsqrtf(var + 1e-5f);
    const float o0 = (v0 - mean) * rs * g[tid] + b[tid];
    const float o1 = (v1 - mean) * rs * g[tid + 256] + b[tid + 256];
    out_bf[(size_t)row * DD + tid]       = f2bf(o0);
    out_bf[(size_t)row * DD + tid + 256] = f2bf(o1);
    if (out_f) {
        out_f[(size_t)row * DD + tid]       = o0;
        out_f[(size_t)row * DD + tid + 256] = o1;
    }
}

// ---------------- bf16 MFMA GEMM: C = A @ W^T + bias (+gelu)(+res) ----------
// A: [M][K] bf16 row-major, W: [Nout][K] bf16 row-major. 128x128 tile, BK=32,
// 256 thr = 4 waves (2x2), each wave 64x64 via 4x4 mfma_f32_16x16x32_bf16.
template <bool GELU, bool RES, bool OUTBF>
__global__ __launch_bounds__(256) void gemm_bf16(
    const short* __restrict__ A, const short* __restrict__ Bw,
    const float* __restrict__ bias, const float* __restrict__ res,
    void* __restrict__ Cout, int M, int Nout, int K) {
    const int bm = blockIdx.y * 128;
    const int bn = blockIdx.x * 128;
    const int tid  = threadIdx.x;
    const int wave = tid >> 6;
    const int lane = tid & 63;
    const int l16  = lane & 15;
    const int quad = lane >> 4;
    const int wr = (wave >> 1) * 64;
    const int wc = (wave & 1) * 64;

    __shared__ short As[128 * 32];  // [row][k] bf16, 8 KB
    __shared__ short Bs[128 * 32];

    f32x4 acc[4][4];
#pragma unroll
    for (int i = 0; i < 4; i++)
#pragma unroll
        for (int j = 0; j < 4; j++) acc[i][j] = (f32x4){0.f, 0.f, 0.f, 0.f};

    for (int k0 = 0; k0 < K; k0 += 32) {
        const short* Ab = A + (size_t)bm * K + k0;
        const short* Bb = Bw + (size_t)bn * K + k0;
        // stage: 512 chunks of 16B each per tile; chunk idx -> row=idx>>2, c=idx&3
#pragma unroll
        for (int j = 0; j < 2; j++) {
            const int idx = j * 256 + wave * 64 + lane;
            const int row = idx >> 2, c = idx & 3;
            short* dstA = (short*)As + (size_t)(j * 256 + wave * 64) * 8;  // wave-uniform
            short* dstB = (short*)Bs + (size_t)(j * 256 + wave * 64) * 8;
            gld_lds16(Ab + (size_t)row * K + c * 8, dstA);
            gld_lds16(Bb + (size_t)row * K + c * 8, dstB);
        }
        __syncthreads();
        bf16x8 af[4], bfr[4];
#pragma unroll
        for (int i = 0; i < 4; i++)
            af[i] = *(const bf16x8*)&As[(wr + i * 16 + l16) * 32 + quad * 8];
#pragma unroll
        for (int j = 0; j < 4; j++)
            bfr[j] = *(const bf16x8*)&Bs[(wc + j * 16 + l16) * 32 + quad * 8];
#pragma unroll
        for (int i = 0; i < 4; i++)
#pragma unroll
            for (int j = 0; j < 4; j++)
                acc[i][j] = __builtin_amdgcn_mfma_f32_16x16x32_bf16(af[i], bfr[j], acc[i][j], 0, 0, 0);
        __syncthreads();
    }
    // epilogue: C/D layout col=l16, row=quad*4+r
#pragma unroll
    for (int i = 0; i < 4; i++) {
#pragma unroll
        for (int r = 0; r < 4; r++) {
            const int row = bm + wr + i * 16 + quad * 4 + r;
#pragma unroll
            for (int j = 0; j < 4; j++) {
                const int col = bn + wc + j * 16 + l16;
                float v = acc[i][j][r] + bias[col];
                if (GELU) v = 0.5f * v * (1.0f + erff(v * 0.70710678118654752f));
                if (RES)  v += res[(size_t)row * Nout + col];
                if (OUTBF) ((short*)Cout)[(size_t)row * Nout + col] = f2bf(v);
                else       ((float*)Cout)[(size_t)row * Nout + col] = v;
            }
        }
    }
}

// ---------------- MFMA flash attention (bf16 qkv in, bf16 ctx out) ----------
__global__ __launch_bounds__(512) void attn_mfma(
    const short* __restrict__ qkv,     // [4096][1536] bf16
    const int* __restrict__ dist,      // [B][N][N]
    const float* __restrict__ dist3d,  // [B][N][N]
    const float* __restrict__ demb,    // [128][16]
    const float* __restrict__ rbfw,    // [16][32]
    const float* __restrict__ rbfb,    // [16]
    short* __restrict__ ctx)           // [4096][512] bf16
{
    const int b    = blockIdx.y;
    const int q0   = blockIdx.x * 16;
    const int tid  = threadIdx.x;
    const int wave = tid >> 6;
    const int lane = tid & 63;
    const int l16  = lane & 15;
    const int quad = lane >> 4;

    __shared__ short Kc[NH * 16 * 32];      // [h][k16][d32] bf16, 16 KB
    __shared__ short Vc[NH * 16 * 32];      // 16 KB
    __shared__ float biasT[16 * 16 * 17];   // [q][k][h pad17] fp32, 17 KB
    __shared__ short Pb[8 * 16 * 32];       // per-wave [q16][k32] bf16, 8 KB

    for (int i = tid; i < 8 * 16 * 32; i += 512) Pb[i] = 0;

    const float scale = 0.17677669529663687f;  // 1/sqrt(32), applied post-MFMA
    bf16x8 qf[2];
#pragma unroll
    for (int h = 0; h < 2; h++) {
        const int hh = wave * 2 + h;
        qf[h] = *(const bf16x8*)(qkv + (size_t)(b * NN + q0 + l16) * TD + hh * DH + quad * 8);
    }
    bf16x8 wf;
#pragma unroll
    for (int j = 0; j < 8; j++) wf[j] = f2bf(rbfw[l16 * NG + quad * 8 + j]);

    f32x4 O[2][2];
    float mrun[2][4], lrun[2][4];
#pragma unroll
    for (int h = 0; h < 2; h++) {
#pragma unroll
        for (int t = 0; t < 2; t++) O[h][t] = (f32x4){0.f, 0.f, 0.f, 0.f};
#pragma unroll
        for (int r = 0; r < 4; r++) { mrun[h][r] = -1e30f; lrun[h][r] = 0.f; }
    }

    const float STEP  = 20.0f / 31.0f;
    const float COEFF = -0.5f / (STEP * STEP);

    for (int c = 0; c < 32; c++) {
        const int k0 = c * 16;
        __syncthreads();
        // ---- async stage K,V chunk via global_load_lds (2048 x 16B chunks) ----
#pragma unroll
        for (int l = 0; l < 4; l++) {
            const int idxb = l * 512 + wave * 64;       // wave-uniform chunk base
            const int idx  = idxb + lane;               // per-lane chunk
            const int kk2  = idx & 1023;
            const int h = kk2 >> 6, k = (kk2 >> 2) & 15, c4 = kk2 & 3;
            const short* src = qkv + (size_t)(b * NN + k0 + k) * TD +
                               DD * (1 + (l >> 1)) + h * 32 + c4 * 8;
            short* dstb = (l < 2 ? (short*)Kc : (short*)Vc) + (size_t)(idxb & 1023) * 8;
            gld_lds16(src, dstb);
        }
        // ---- bias MFMA: wave handles q-rows wave*2, wave*2+1 ----
#pragma unroll
        for (int g = 0; g < 2; g++) {
            const int qloc = wave * 2 + g;
            const size_t rowbase = ((size_t)(b * NN) + q0 + qloc) * NN + k0;
            const float d3 = dist3d[rowbase + l16];
            bf16x8 ef;
#pragma unroll
            for (int j = 0; j < 8; j++) {
                const float t = d3 - (float)(quad * 8 + j) * STEP;
                ef[j] = f2bf(__expf(COEFF * t * t));
            }
            f32x4 cc;
            const float rb = rbfb[l16];
#pragma unroll
            for (int r = 0; r < 4; r++) {
                int dc = dist[rowbase + quad * 4 + r];
                dc = min(max(dc, 0), MAXD - 1);
                cc[r] = demb[dc * NH + l16] + rb;
            }
            const f32x4 dres = __builtin_amdgcn_mfma_f32_16x16x32_bf16(ef, wf, cc, 0, 0, 0);
#pragma unroll
            for (int r = 0; r < 4; r++)
                biasT[(qloc * 16 + quad * 4 + r) * 17 + l16] = dres[r];
        }
        __syncthreads();
        // ---- per-head: QK^T MFMA, bias, online softmax, PV MFMA ----
#pragma unroll
        for (int h = 0; h < 2; h++) {
            const int hh = wave * 2 + h;
            const bf16x8 kf = *(const bf16x8*)&Kc[hh * 512 + l16 * 32 + quad * 8];
            f32x4 s = __builtin_amdgcn_mfma_f32_16x16x32_bf16(
                qf[h], kf, (f32x4){0.f, 0.f, 0.f, 0.f}, 0, 0, 0);
            float sv[4], mx[4], al[4], pv[4], ps[4];
#pragma unroll
            for (int r = 0; r < 4; r++) {
                sv[r] = s[r] * scale + biasT[((quad * 4 + r) * 16 + l16) * 17 + hh];
                mx[r] = sv[r];
            }
#pragma unroll
            for (int m = 1; m < 16; m <<= 1)
#pragma unroll
                for (int r = 0; r < 4; r++) mx[r] = fmaxf(mx[r], __shfl_xor(mx[r], m));
#pragma unroll
            for (int r = 0; r < 4; r++) {
                const float mn = fmaxf(mrun[h][r], mx[r]);
                al[r] = __expf(mrun[h][r] - mn);
                pv[r] = __expf(sv[r] - mn);
                mrun[h][r] = mn;
                ps[r] = pv[r];
            }
#pragma unroll
            for (int m = 1; m < 16; m <<= 1)
#pragma unroll
                for (int r = 0; r < 4; r++) ps[r] += __shfl_xor(ps[r], m);
#pragma unroll
            for (int r = 0; r < 4; r++) {
                lrun[h][r] = lrun[h][r] * al[r] + ps[r];
                Pb[wave * 512 + (quad * 4 + r) * 32 + l16] = f2bf(pv[r]);
#pragma unroll
                for (int t = 0; t < 2; t++) O[h][t][r] *= al[r];
            }
            const bf16x8 pf = *(const bf16x8*)&Pb[wave * 512 + l16 * 32 + quad * 8];
#pragma unroll
            for (int t = 0; t < 2; t++) {
                bf16x8 vf;
                if (quad < 2) {
#pragma unroll
                    for (int j = 0; j < 8; j++)
                        vf[j] = Vc[hh * 512 + (quad * 8 + j) * 32 + t * 16 + l16];
                } else {
#pragma unroll
                    for (int j = 0; j < 8; j++) vf[j] = 0;
                }
                O[h][t] = __builtin_amdgcn_mfma_f32_16x16x32_bf16(pf, vf, O[h][t], 0, 0, 0);
            }
        }
    }
#pragma unroll
    for (int h = 0; h < 2; h++) {
        const int hh = wave * 2 + h;
#pragma unroll
        for (int r = 0; r < 4; r++) {
            const float rinv = 1.0f / lrun[h][r];
            const size_t row = (size_t)(b * NN + q0 + quad * 4 + r);
#pragma unroll
            for (int t = 0; t < 2; t++)
                ctx[row * DD + hh * DH + t * 16 + l16] = f2bf(O[h][t][r] * rinv);
        }
    }
}

extern "C" void kernel_launch(void* const* d_in, const int* in_sizes, int n_in,
                              void* d_out, int out_size, void* d_ws, size_t ws_size,
                              hipStream_t stream) {
    const float* x      = (const float*)d_in[0];
    const int*   dist   = (const int*)d_in[1];
    const float* dist3d = (const float*)d_in[2];
    const float* n1g    = (const float*)d_in[3];
    const float* n1b    = (const float*)d_in[4];
    const float* win    = (const float*)d_in[5];
    const float* bin    = (const float*)d_in[6];
    const float* wo     = (const float*)d_in[7];
    const float* bo     = (const float*)d_in[8];
    const float* demb   = (const float*)d_in[9];
    const float* rbfw   = (const float*)d_in[10];
    const float* rbfb   = (const float*)d_in[11];
    const float* n2g    = (const float*)d_in[12];
    const float* n2b    = (const float*)d_in[13];
    const float* w1     = (const float*)d_in[14];
    const float* b1     = (const float*)d_in[15];
    const float* w2     = (const float*)d_in[16];
    const float* b2     = (const float*)d_in[17];

    char* p = (char*)d_ws;
    short* h_bf   = (short*)p; p += (size_t)4096 * 512 * 2;
    float* h_f    = (float*)p; p += (size_t)4096 * 512 * 4;
    short* qkv_bf = (short*)p; p += (size_t)4096 * 1536 * 2;
    short* ctx_bf = (short*)p; p += (size_t)4096 * 512 * 2;
    float* hres   = (float*)p; p += (size_t)4096 * 512 * 4;
    short* h2_bf  = (short*)p; p += (size_t)4096 * 512 * 2;
    short* mid_bf = (short*)p; p += (size_t)4096 * 2048 * 2;
    short* win_bf = (short*)p; p += (size_t)1536 * 512 * 2;
    short* wo_bf  = (short*)p; p += (size_t)512 * 512 * 2;
    short* w1_bf  = (short*)p; p += (size_t)2048 * 512 * 2;
    short* w2_bf  = (short*)p; p += (size_t)512 * 2048 * 2;

    const int M = BB * NN;  // 4096

    cvt_weights<<<dim3(1024, 4), 256, 0, stream>>>(
        win, wo, w1, w2, win_bf, wo_bf, w1_bf, w2_bf,
        1536 * 512, 512 * 512, 2048 * 512, 512 * 2048);
    ln_kernel<<<M, 256, 0, stream>>>(x, n1g, n1b, h_bf, h_f);
    gemm_bf16<false, false, true><<<dim3(12, 32), 256, 0, stream>>>(
        h_bf, win_bf, bin, nullptr, qkv_bf, M, TD, DD);
    attn_mfma<<<dim3(NN / 16, BB), 512, 0, stream>>>(
        qkv_bf, dist, dist3d, demb, rbfw, rbfb, ctx_bf);
    gemm_bf16<false, true, false><<<dim3(4, 32), 256, 0, stream>>>(
        ctx_bf, wo_bf, bo, h_f, hres, M, DD, DD);
    ln_kernel<<<M, 256, 0, stream>>>(hres, n2g, n2b, h2_bf, nullptr);
    gemm_bf16<true, false, true><<<dim3(16, 32), 256, 0, stream>>>(
        h2_bf, w1_bf, b1, nullptr, mid_bf, M, 2048, DD);
    gemm_bf16<false, true, false><<<dim3(4, 32), 256, 0, stream>>>(
        mid_bf, w2_bf, b2, hres, (float*)d_out, M, DD, 2048);
}

// Round 4
// 282.254 us; speedup vs baseline: 12.4103x; 1.2454x over previous
//
#include <hip/hip_runtime.h>
#include <hip/hip_bf16.h>
#include <math.h>

#define BB 8
#define NN 512
#define DD 512
#define NH 16
#define DH 32
#define TD 1536
#define NG 32
#define MAXD 128

typedef __attribute__((ext_vector_type(8))) short bf16x8;
typedef __attribute__((ext_vector_type(4))) float f32x4;

__device__ inline short f2bf(float x) {
    __hip_bfloat16 h = __float2bfloat16(x);
    return *reinterpret_cast<short*>(&h);
}

// async 16B global->LDS. lds dest must be WAVE-UNIFORM base; lane i lands at base + i*16.
__device__ inline void gld_lds16(const void* g, void* l) {
    __builtin_amdgcn_global_load_lds(
        (const __attribute__((address_space(1))) unsigned int*)g,
        (__attribute__((address_space(3))) unsigned int*)l, 16, 0, 0);
}

// ---------------- weight fp32 -> bf16 convert (4 arrays in one launch) ------
__global__ __launch_bounds__(256) void cvt_weights(
    const float* __restrict__ s0, const float* __restrict__ s1,
    const float* __restrict__ s2, const float* __restrict__ s3,
    short* __restrict__ d0, short* __restrict__ d1,
    short* __restrict__ d2, short* __restrict__ d3,
    int n0, int n1, int n2, int n3) {
    const float* s; short* d; int n;
    switch (blockIdx.y) {
        case 0: s = s0; d = d0; n = n0; break;
        case 1: s = s1; d = d1; n = n1; break;
        case 2: s = s2; d = d2; n = n2; break;
        default: s = s3; d = d3; n = n3; break;
    }
    const int i = (blockIdx.x * 256 + threadIdx.x) * 4;
    if (i >= n) return;
    const float4 v = *(const float4*)(s + i);
    short4 o;
    o.x = f2bf(v.x); o.y = f2bf(v.y); o.z = f2bf(v.z); o.w = f2bf(v.w);
    *(short4*)(d + i) = o;
}

// ---------------- LayerNorm: bf16 out (+ optional fp32 copy for residual) ---
__global__ __launch_bounds__(256) void ln_kernel(const float* __restrict__ x,
                                                 const float* __restrict__ g,
                                                 const float* __restrict__ b,
                                                 short* __restrict__ out_bf,
                                                 float* __restrict__ out_f) {
    const int row = blockIdx.x;
    const int tid = threadIdx.x;
    const float* xr = x + (size_t)row * DD;
    float v0 = xr[tid], v1 = xr[tid + 256];
    __shared__ float s1[256], s2[256];
    s1[tid] = v0 + v1;
    s2[tid] = v0 * v0 + v1 * v1;
    __syncthreads();
    for (int off = 128; off > 0; off >>= 1) {
        if (tid < off) { s1[tid] += s1[tid + off]; s2[tid] += s2[tid + off]; }
        __syncthreads();
    }
    const float mean = s1[0] * (1.0f / DD);
    const float var  = s2[0] * (1.0f / DD) - mean * mean;
    const float rs   = rsqrtf(var + 1e-5f);
    const float o0 = (v0 - mean) * rs * g[tid] + b[tid];
    const float o1 = (v1 - mean) * rs * g[tid + 256] + b[tid + 256];
    out_bf[(size_t)row * DD + tid]       = f2bf(o0);
    out_bf[(size_t)row * DD + tid + 256] = f2bf(o1);
    if (out_f) {
        out_f[(size_t)row * DD + tid]       = o0;
        out_f[(size_t)row * DD + tid + 256] = o1;
    }
}

// ---------------- bf16 MFMA GEMM: C = A @ W^T + bias (+gelu)(+res) ----------
template <bool GELU, bool RES, bool OUTBF>
__global__ __launch_bounds__(256) void gemm_bf16(
    const short* __restrict__ A, const short* __restrict__ Bw,
    const float* __restrict__ bias, const float* __restrict__ res,
    void* __restrict__ Cout, int M, int Nout, int K) {
    const int bm = blockIdx.y * 128;
    const int bn = blockIdx.x * 128;
    const int tid  = threadIdx.x;
    const int wave = tid >> 6;
    const int lane = tid & 63;
    const int l16  = lane & 15;
    const int quad = lane >> 4;
    const int wr = (wave >> 1) * 64;
    const int wc = (wave & 1) * 64;

    __shared__ short As[128 * 32];
    __shared__ short Bs[128 * 32];

    f32x4 acc[4][4];
#pragma unroll
    for (int i = 0; i < 4; i++)
#pragma unroll
        for (int j = 0; j < 4; j++) acc[i][j] = (f32x4){0.f, 0.f, 0.f, 0.f};

    for (int k0 = 0; k0 < K; k0 += 32) {
        const short* Ab = A + (size_t)bm * K + k0;
        const short* Bb = Bw + (size_t)bn * K + k0;
#pragma unroll
        for (int j = 0; j < 2; j++) {
            const int idx = j * 256 + wave * 64 + lane;
            const int row = idx >> 2, c = idx & 3;
            short* dstA = (short*)As + (size_t)(j * 256 + wave * 64) * 8;
            short* dstB = (short*)Bs + (size_t)(j * 256 + wave * 64) * 8;
            gld_lds16(Ab + (size_t)row * K + c * 8, dstA);
            gld_lds16(Bb + (size_t)row * K + c * 8, dstB);
        }
        __syncthreads();
        bf16x8 af[4], bfr[4];
#pragma unroll
        for (int i = 0; i < 4; i++)
            af[i] = *(const bf16x8*)&As[(wr + i * 16 + l16) * 32 + quad * 8];
#pragma unroll
        for (int j = 0; j < 4; j++)
            bfr[j] = *(const bf16x8*)&Bs[(wc + j * 16 + l16) * 32 + quad * 8];
#pragma unroll
        for (int i = 0; i < 4; i++)
#pragma unroll
            for (int j = 0; j < 4; j++)
                acc[i][j] = __builtin_amdgcn_mfma_f32_16x16x32_bf16(af[i], bfr[j], acc[i][j], 0, 0, 0);
        __syncthreads();
    }
#pragma unroll
    for (int i = 0; i < 4; i++) {
#pragma unroll
        for (int r = 0; r < 4; r++) {
            const int row = bm + wr + i * 16 + quad * 4 + r;
#pragma unroll
            for (int j = 0; j < 4; j++) {
                const int col = bn + wc + j * 16 + l16;
                float v = acc[i][j][r] + bias[col];
                if (GELU) v = 0.5f * v * (1.0f + erff(v * 0.70710678118654752f));
                if (RES)  v += res[(size_t)row * Nout + col];
                if (OUTBF) ((short*)Cout)[(size_t)row * Nout + col] = f2bf(v);
                else       ((float*)Cout)[(size_t)row * Nout + col] = v;
            }
        }
    }
}

// ---------------- MFMA flash attention, split-K, no-max softmax ----------
// 512 blocks: b = blk&7 (XCD-local), half = (blk>>3)&1, qtile = blk>>4.
// Each block: 16 q-rows x 256 keys (16 chunks of 16). Outputs unnormalized
// partial O (fp32) + partial row-sums l; combine kernel normalizes.
__global__ __launch_bounds__(512) void attn_mfma(
    const short* __restrict__ qkv,     // [4096][1536] bf16
    const int* __restrict__ dist,      // [B][N][N]
    const float* __restrict__ dist3d,  // [B][N][N]
    const float* __restrict__ demb,    // [128][16]
    const float* __restrict__ rbfw,    // [16][32]
    const float* __restrict__ rbfb,    // [16]
    float* __restrict__ O_part,        // [2][4096][512] fp32
    float* __restrict__ l_part)        // [2][4096][16]  fp32
{
    const int blk  = blockIdx.x;
    const int b    = blk & 7;
    const int half = (blk >> 3) & 1;
    const int q0   = (blk >> 4) * 16;
    const int tid  = threadIdx.x;
    const int wave = tid >> 6;
    const int lane = tid & 63;
    const int l16  = lane & 15;
    const int quad = lane >> 4;

    __shared__ short Kc[NH * 16 * 32];      // [h][k16][d32] bf16, 16 KB
    __shared__ short Vc[NH * 16 * 32];      // 16 KB
    __shared__ float biasT[16 * 16 * 17];   // [q][k][h pad17] fp32, 17 KB
    __shared__ short Pb[8 * 16 * 32];       // per-wave [q16][k32] bf16, 8 KB

    for (int i = tid; i < 8 * 16 * 32; i += 512) Pb[i] = 0;

    const float scale = 0.17677669529663687f;  // 1/sqrt(32)
    bf16x8 qf[2];
#pragma unroll
    for (int h = 0; h < 2; h++) {
        const int hh = wave * 2 + h;
        qf[h] = *(const bf16x8*)(qkv + (size_t)(b * NN + q0 + l16) * TD + hh * DH + quad * 8);
    }
    bf16x8 wf;
#pragma unroll
    for (int j = 0; j < 8; j++) wf[j] = f2bf(rbfw[l16 * NG + quad * 8 + j]);

    f32x4 O[2][2];
    float lsum[2][4];
#pragma unroll
    for (int h = 0; h < 2; h++) {
#pragma unroll
        for (int t = 0; t < 2; t++) O[h][t] = (f32x4){0.f, 0.f, 0.f, 0.f};
#pragma unroll
        for (int r = 0; r < 4; r++) lsum[h][r] = 0.f;
    }

    const float STEP  = 20.0f / 31.0f;
    const float COEFF = -0.5f / (STEP * STEP);

    for (int c = 0; c < 16; c++) {
        const int k0 = half * 256 + c * 16;
        __syncthreads();
        // ---- async stage K,V chunk (2048 x 16B chunks) ----
#pragma unroll
        for (int l = 0; l < 4; l++) {
            const int idxb = l * 512 + wave * 64;
            const int idx  = idxb + lane;
            const int kk2  = idx & 1023;
            const int h = kk2 >> 6, k = (kk2 >> 2) & 15, c4 = kk2 & 3;
            const short* src = qkv + (size_t)(b * NN + k0 + k) * TD +
                               DD * (1 + (l >> 1)) + h * 32 + c4 * 8;
            short* dstb = (l < 2 ? (short*)Kc : (short*)Vc) + (size_t)(idxb & 1023) * 8;
            gld_lds16(src, dstb);
        }
        // ---- bias MFMA: wave handles q-rows wave*2, wave*2+1 ----
#pragma unroll
        for (int g = 0; g < 2; g++) {
            const int qloc = wave * 2 + g;
            const size_t rowbase = ((size_t)(b * NN) + q0 + qloc) * NN + k0;
            const float d3 = dist3d[rowbase + l16];
            bf16x8 ef;
#pragma unroll
            for (int j = 0; j < 8; j++) {
                const float t = d3 - (float)(quad * 8 + j) * STEP;
                ef[j] = f2bf(__expf(COEFF * t * t));
            }
            f32x4 cc;
            const float rb = rbfb[l16];
#pragma unroll
            for (int r = 0; r < 4; r++) {
                int dc = dist[rowbase + quad * 4 + r];
                dc = min(max(dc, 0), MAXD - 1);
                cc[r] = demb[dc * NH + l16] + rb;
            }
            const f32x4 dres = __builtin_amdgcn_mfma_f32_16x16x32_bf16(ef, wf, cc, 0, 0, 0);
#pragma unroll
            for (int r = 0; r < 4; r++)
                biasT[(qloc * 16 + quad * 4 + r) * 17 + l16] = dres[r];
        }
        __syncthreads();
        // ---- per-head: QK^T MFMA, bias, exp (no max shift), PV MFMA ----
#pragma unroll
        for (int h = 0; h < 2; h++) {
            const int hh = wave * 2 + h;
            const bf16x8 kf = *(const bf16x8*)&Kc[hh * 512 + l16 * 32 + quad * 8];
            f32x4 s = __builtin_amdgcn_mfma_f32_16x16x32_bf16(
                qf[h], kf, (f32x4){0.f, 0.f, 0.f, 0.f}, 0, 0, 0);
            float pv[4];
#pragma unroll
            for (int r = 0; r < 4; r++) {
                float sv = s[r] * scale + biasT[((quad * 4 + r) * 16 + l16) * 17 + hh];
                sv = fminf(sv, 20.f);
                pv[r] = __expf(sv);
                lsum[h][r] += pv[r];
                Pb[wave * 512 + (quad * 4 + r) * 32 + l16] = f2bf(pv[r]);
            }
            const bf16x8 pf = *(const bf16x8*)&Pb[wave * 512 + l16 * 32 + quad * 8];
#pragma unroll
            for (int t = 0; t < 2; t++) {
                bf16x8 vf;
                if (quad < 2) {
#pragma unroll
                    for (int j = 0; j < 8; j++)
                        vf[j] = Vc[hh * 512 + (quad * 8 + j) * 32 + t * 16 + l16];
                } else {
#pragma unroll
                    for (int j = 0; j < 8; j++) vf[j] = 0;
                }
                O[h][t] = __builtin_amdgcn_mfma_f32_16x16x32_bf16(pf, vf, O[h][t], 0, 0, 0);
            }
        }
    }
    // ---- epilogue: reduce lsum across the 16-lane k groups, write partials --
    const size_t halfoff = (size_t)half * 4096;
#pragma unroll
    for (int h = 0; h < 2; h++) {
        const int hh = wave * 2 + h;
#pragma unroll
        for (int m = 1; m < 16; m <<= 1)
#pragma unroll
            for (int r = 0; r < 4; r++) lsum[h][r] += __shfl_xor(lsum[h][r], m);
#pragma unroll
        for (int r = 0; r < 4; r++) {
            const size_t row = (size_t)(b * NN + q0 + quad * 4 + r);
#pragma unroll
            for (int t = 0; t < 2; t++)
                O_part[(halfoff + row) * DD + hh * DH + t * 16 + l16] = O[h][t][r];
            if (l16 == 0) l_part[(halfoff + row) * NH + hh] = lsum[h][r];
        }
    }
}

// ---------------- combine split-K partials -> ctx bf16 ----------------
__global__ __launch_bounds__(256) void attn_combine(
    const float* __restrict__ O_part, const float* __restrict__ l_part,
    short* __restrict__ ctx) {
    const int e = (blockIdx.x * 256 + threadIdx.x) * 4;
    const int row = e >> 9, d = e & 511, h = d >> 5;
    const float4 o0 = *(const float4*)(O_part + e);
    const float4 o1 = *(const float4*)(O_part + (size_t)4096 * 512 + e);
    const float l = l_part[row * NH + h] + l_part[4096 * NH + row * NH + h];
    const float rinv = 1.0f / l;
    short4 o;
    o.x = f2bf((o0.x + o1.x) * rinv);
    o.y = f2bf((o0.y + o1.y) * rinv);
    o.z = f2bf((o0.z + o1.z) * rinv);
    o.w = f2bf((o0.w + o1.w) * rinv);
    *(short4*)(ctx + e) = o;
}

extern "C" void kernel_launch(void* const* d_in, const int* in_sizes, int n_in,
                              void* d_out, int out_size, void* d_ws, size_t ws_size,
                              hipStream_t stream) {
    const float* x      = (const float*)d_in[0];
    const int*   dist   = (const int*)d_in[1];
    const float* dist3d = (const float*)d_in[2];
    const float* n1g    = (const float*)d_in[3];
    const float* n1b    = (const float*)d_in[4];
    const float* win    = (const float*)d_in[5];
    const float* bin    = (const float*)d_in[6];
    const float* wo     = (const float*)d_in[7];
    const float* bo     = (const float*)d_in[8];
    const float* demb   = (const float*)d_in[9];
    const float* rbfw   = (const float*)d_in[10];
    const float* rbfb   = (const float*)d_in[11];
    const float* n2g    = (const float*)d_in[12];
    const float* n2b    = (const float*)d_in[13];
    const float* w1     = (const float*)d_in[14];
    const float* b1     = (const float*)d_in[15];
    const float* w2     = (const float*)d_in[16];
    const float* b2     = (const float*)d_in[17];

    char* p = (char*)d_ws;
    short* h_bf   = (short*)p; p += (size_t)4096 * 512 * 2;
    float* h_f    = (float*)p; p += (size_t)4096 * 512 * 4;
    short* qkv_bf = (short*)p; p += (size_t)4096 * 1536 * 2;
    short* ctx_bf = (short*)p; p += (size_t)4096 * 512 * 2;
    float* hres   = (float*)p; p += (size_t)4096 * 512 * 4;
    short* h2_bf  = (short*)p; p += (size_t)4096 * 512 * 2;
    short* mid_bf = (short*)p; p += (size_t)4096 * 2048 * 2;
    short* win_bf = (short*)p; p += (size_t)1536 * 512 * 2;
    short* wo_bf  = (short*)p; p += (size_t)512 * 512 * 2;
    short* w1_bf  = (short*)p; p += (size_t)2048 * 512 * 2;
    short* w2_bf  = (short*)p; p += (size_t)512 * 2048 * 2;
    float* O_part = (float*)p; p += (size_t)2 * 4096 * 512 * 4;
    float* l_part = (float*)p; p += (size_t)2 * 4096 * 16 * 4;

    const int M = BB * NN;  // 4096

    cvt_weights<<<dim3(1024, 4), 256, 0, stream>>>(
        win, wo, w1, w2, win_bf, wo_bf, w1_bf, w2_bf,
        1536 * 512, 512 * 512, 2048 * 512, 512 * 2048);
    ln_kernel<<<M, 256, 0, stream>>>(x, n1g, n1b, h_bf, h_f);
    gemm_bf16<false, false, true><<<dim3(12, 32), 256, 0, stream>>>(
        h_bf, win_bf, bin, nullptr, qkv_bf, M, TD, DD);
    attn_mfma<<<512, 512, 0, stream>>>(
        qkv_bf, dist, dist3d, demb, rbfw, rbfb, O_part, l_part);
    attn_combine<<<2048, 256, 0, stream>>>(O_part, l_part, ctx_bf);
    gemm_bf16<false, true, false><<<dim3(4, 32), 256, 0, stream>>>(
        ctx_bf, wo_bf, bo, h_f, hres, M, DD, DD);
    ln_kernel<<<M, 256, 0, stream>>>(hres, n2g, n2b, h2_bf, nullptr);
    gemm_bf16<true, false, true><<<dim3(16, 32), 256, 0, stream>>>(
        h2_bf, w1_bf, b1, nullptr, mid_bf, M, 2048, DD);
    gemm_bf16<false, true, false><<<dim3(4, 32), 256, 0, stream>>>(
        mid_bf, w2_bf, b2, hres, (float*)d_out, M, DD, 2048);
}